// Round 17
// baseline (96.030 us; speedup 1.0000x reference)
//
#include <hip/hip_runtime.h>
#include <hip/hip_bf16.h>
#include <stdint.h>
#include <math.h>

typedef __attribute__((ext_vector_type(8))) short bf16x8;
typedef __attribute__((ext_vector_type(4))) float f32x4;

#define HQ 2048
#define HK 2048
#define NH 8
#define ND 32
#define NC 256

union U8 { uint32_t u[4]; bf16x8 v; };

__device__ __forceinline__ uint16_t f2bf(float f) {
  uint32_t u = __float_as_uint(f);
  u += 0x7FFFu + ((u >> 16) & 1u);   // RNE
  return (uint16_t)(u >> 16);
}
__device__ __forceinline__ uint32_t pack2bf(float a, float b) {
  return (uint32_t)f2bf(a) | ((uint32_t)f2bf(b) << 16);
}
// single-instruction RNE pack (v_cvt_pk_bf16_f32): lo=bf16(a), hi=bf16(b)
__device__ __forceinline__ uint32_t cvt2bf(float a, float b) {
  uint32_t r;
  asm("v_cvt_pk_bf16_f32 %0, %1, %2" : "=v"(r) : "v"(a), "v"(b));
  return r;
}
// 64B rows (32 bf16), 4 pieces of 16B
__device__ __forceinline__ int swz64(int row, int piece) {
  int s = (((row >> 3) & 1) << 1) | ((row >> 1) & 1);
  return row * 64 + ((piece ^ s) << 4);
}
__device__ __forceinline__ f32x4 mfma32(bf16x8 a, bf16x8 b, f32x4 c) {
  return __builtin_amdgcn_mfma_f32_16x16x32_bf16(a, b, c, 0, 0, 0);
}
// async global->LDS DMA, 16B per lane; dst wave-uniform (HW: dst+lane*16)
__device__ __forceinline__ void dma16(const void* g, void* l) {
  __builtin_amdgcn_global_load_lds(
      (const __attribute__((address_space(1))) uint32_t*)g,
      (__attribute__((address_space(3))) uint32_t*)l, 16, 0, 0);
}

// ---------------- projections: q,k,v,g -----------------------------------
// grid 256: bx&63 = Mblock(64 rows), bx>>6 = proj id. Block computes ALL 256
// output cols (X staged ONCE -> X traffic 48->12MB vs old 4-Nb split).
__global__ __launch_bounds__(256) void proj_kernel(
    const float* __restrict__ qx, const float* __restrict__ kvx,
    const float* __restrict__ Wq, const float* __restrict__ Wk,
    const float* __restrict__ Wv, const float* __restrict__ Wg,
    const float* __restrict__ bg,
    uint16_t* __restrict__ q_p, uint16_t* __restrict__ k_p,
    uint16_t* __restrict__ v_p, float* __restrict__ g_ws)
{
  const int bx = blockIdx.x;
  const int Mb = bx & 63, p = bx >> 6;
  const int Mbase = Mb * 64;
  const float* X = (p == 0 || p == 3) ? qx : kvx;
  const float* W = (p == 0) ? Wq : (p == 1) ? Wk : (p == 2) ? Wv : Wg;

  __shared__ __align__(16) uint16_t smem[10240]; // sX 64x32 (4KB) | sW 256x32 (16KB)
  uint16_t* sX = smem;
  uint16_t* sW = smem + 2048;

  const int tid = threadIdx.x;
  const int l = tid & 63, w = tid >> 6;
  const int qq = l & 15, g = l >> 4;
  const int row = tid >> 2, gp = tid & 3;

  f32x4 acc[16] = {};

  for (int ks = 0; ks < 8; ++ks) {
    const float* xs = X + (size_t)(Mbase + row) * 256 + ks * 32 + gp * 8;
    f32x4 x0 = *(const f32x4*)xs;
    f32x4 x1 = *(const f32x4*)(xs + 4);
    f32x4 wv[4][2];
#pragma unroll
    for (int j = 0; j < 4; ++j) {
      const float* ws_ = W + (size_t)(j * 64 + row) * 256 + ks * 32 + gp * 8;
      wv[j][0] = *(const f32x4*)ws_;
      wv[j][1] = *(const f32x4*)(ws_ + 4);
    }
    __syncthreads();
    {
      U8 ux;
      ux.u[0] = pack2bf(x0[0], x0[1]); ux.u[1] = pack2bf(x0[2], x0[3]);
      ux.u[2] = pack2bf(x1[0], x1[1]); ux.u[3] = pack2bf(x1[2], x1[3]);
      *(bf16x8*)((char*)sX + swz64(row, gp)) = ux.v;
    }
#pragma unroll
    for (int j = 0; j < 4; ++j) {
      U8 uw;
      uw.u[0] = pack2bf(wv[j][0][0], wv[j][0][1]);
      uw.u[1] = pack2bf(wv[j][0][2], wv[j][0][3]);
      uw.u[2] = pack2bf(wv[j][1][0], wv[j][1][1]);
      uw.u[3] = pack2bf(wv[j][1][2], wv[j][1][3]);
      *(bf16x8*)((char*)sW + swz64(j * 64 + row, gp)) = uw.v;
    }
    __syncthreads();
    bf16x8 a = *(bf16x8*)((char*)sX + swz64(w * 16 + qq, g));
#pragma unroll
    for (int nf = 0; nf < 16; ++nf) {
      bf16x8 bb = *(bf16x8*)((char*)sW + swz64(nf * 16 + qq, g));
      acc[nf] = mfma32(a, bb, acc[nf]);
    }
  }

  if (p == 2) {
    // transpose epilogue -> v_p[B,H,D,K], 4 sequential 64x64 sub-tiles
    const int bb_ = Mbase >> 11;
#pragma unroll 1
    for (int nb = 0; nb < 4; ++nb) {
      __syncthreads();
#pragma unroll
      for (int nf2 = 0; nf2 < 4; ++nf2) {
        int n_loc = nf2 * 16 + qq;
#pragma unroll
        for (int r = 0; r < 4; ++r) {
          int m_loc = w * 16 + 4 * g + r;
          int byte = n_loc * 128 + ((((m_loc >> 3) ^ (n_loc & 7)) << 4)) + (m_loc & 7) * 2;
          *(uint16_t*)((char*)smem + byte) = f2bf(acc[nb * 4 + nf2][r]);
        }
      }
      __syncthreads();
      const int n_loc = tid >> 2, mp = tid & 3;
      const int ng = nb * 64 + n_loc;
      const int hh = ng >> 5, dd = ng & 31;
#pragma unroll
      for (int jj = 0; jj < 2; ++jj) {
        int piece = mp * 2 + jj;
        bf16x8 vv = *(bf16x8*)((char*)smem + n_loc * 128 + ((piece ^ (n_loc & 7)) << 4));
        int seq = (Mbase & 2047) + piece * 8;
        *(bf16x8*)(v_p + ((size_t)(bb_ * NH + hh) * ND + dd) * (size_t)HK + seq) = vv;
      }
    }
    return;
  }

#pragma unroll
  for (int nf = 0; nf < 16; ++nf) {
    int n = nf * 16 + qq;
#pragma unroll
    for (int r = 0; r < 4; ++r) {
      int m = Mbase + w * 16 + 4 * g + r;
      float val = acc[nf][r];
      if (p == 0) {
        val *= 0.17677669529663687f; // 1/sqrt(32)
        int bb_ = m >> 11, seq = m & 2047, hh = n >> 5, dd = n & 31;
        q_p[((size_t)(bb_ * NH + hh) * HQ + seq) * ND + dd] = f2bf(val);
      } else if (p == 1) {
        int bb_ = m >> 11, seq = m & 2047, hh = n >> 5, dd = n & 31;
        k_p[((size_t)(bb_ * NH + hh) * HK + seq) * ND + dd] = f2bf(val);
      } else { // p == 3 : gate
        g_ws[(size_t)m * NC + n] = 1.f / (1.f + __expf(-(val + bg[n])));
      }
    }
  }
}

// ---------------- fused attention -----------------------------------------
// grid 512 x 512 thr: bx&3=khq (K quarter, 512 k), (bx>>2)&7=h, bx>>5=qt
// (128 q rows). 8 waves; wave wq owns q-rows qt*128+wq*16..+15, BOTH batches.
// k-tile 32 -> 16 iters. Per iter per wave exactly 3 DMAs -> counted vmcnt(3).
// LDS 56KB -> 2 blocks/CU. v_cvt_pk_bf16_f32 packing.  (R15-proven body.)
// Unnormalized softmax; 4-way K-split partials merged in outproj.
__global__ __launch_bounds__(512, 4) void attn_kernel(
    const uint16_t* __restrict__ q_p, const uint16_t* __restrict__ k_p,
    const uint16_t* __restrict__ v_p, const float* __restrict__ bias_mask,
    const float* __restrict__ bias_pair,
    float* __restrict__ O_ws, float* __restrict__ l_ws)
{
  const int bx = blockIdx.x;
  const int khq = bx & 3, h = (bx >> 2) & 7, qt = bx >> 5;

  __shared__ __align__(16) char LDS[57344];    // 56 KB
  char* sK = LDS;             // 2buf x 2b x 2KB = 8KB
  char* sV = LDS + 8192;      // 2buf x 2b x 2KB = 8KB
  char* sP = LDS + 16384;     // 2buf x 16KB     = 32KB
  char* sBM = LDS + 49152;    // 2 copies x (2b x 2KB) = 8KB

  const int tid = threadIdx.x;
  const int l = tid & 63, wq = tid >> 6;       // wq 0..7
  const int qq = l & 15, g = l >> 4;
  const int q_glob = qt * 128 + wq * 16 + qq;

  // Q B-fragments for both batches (hoisted)
  bf16x8 qf0 = *(const bf16x8*)(q_p + ((size_t)h * HQ + q_glob) * ND + g * 8);
  bf16x8 qf1 = *(const bf16x8*)(q_p + ((size_t)(NH + h) * HQ + q_glob) * ND + g * 8);

  // ---- role staging: waves 0-3 stage K, waves 4-7 stage V ----
  const int rw = wq & 3;                 // role sub-index
  const int bsel = rw >> 1, hsel = rw & 1;
  const char* roleSrc;
  int roleStride;
  char* roleDst;                          // + dbi*4096 at use
  if (wq < 4) {
    int B = hsel * 1024 + l * 16;
    int Lr = B >> 7, cpos = l & 7;
    int hp = cpos ^ (Lr & 7);
    int half = hp >> 2, pc = hp & 3;
    int s = Lr * 2 + half, F = s >> 4, qs = s & 15;
    int krow = 8 * (qs >> 2) + (qs & 3) + 4 * F;
    roleSrc = (const char*)k_p + (size_t)(bsel * NH + h) * HK * ND * 2
              + khq * 32768 + krow * 64 + pc * 16;
    roleStride = 2048;
    roleDst = sK + bsel * 2048 + hsel * 1024;
  } else {
    int B = hsel * 1024 + l * 16;
    int d = B >> 6, cpos = l & 3;
    int gs = cpos ^ ((d ^ (d >> 2)) & 3);
    roleSrc = (const char*)v_p + (size_t)(bsel * NH + h) * ND * (size_t)HK * 2
              + khq * 1024 + (size_t)d * (HK * 2) + gs * 16;
    roleStride = 64;
    roleDst = sV + bsel * 2048 + hsel * 1024;
  }
  // bias_pair: each wave stages its own 16 q-rows x 128B = 2 x 1KB dma.
  const char* pSrc0; const char* pSrc1;
  {
    const char* bpBlk = (const char*)bias_pair
        + ((size_t)h * HQ + qt * 128) * (size_t)HK * 4 + khq * 2048;
#define BP_SRC(jj) ({ int row = wq * 16 + (jj) * 8 + (l >> 3); \
                      int gs = (l & 7) ^ (row & 7); \
                      bpBlk + (size_t)row * (HK * 4) + gs * 16; })
    pSrc0 = BP_SRC(0); pSrc1 = BP_SRC(1);
#undef BP_SRC
  }

  // ---- reader byte offsets (loop-invariant; R11-proven) ----
  int afOff[2], vaOff[2], bpOff[2];
#pragma unroll
  for (int F = 0; F < 2; ++F) {
    int Lr = 8 * F + (qq >> 1);
    afOff[F] = Lr * 128 + ((((qq & 1) * 4 + g) ^ (Lr & 7)) << 4);
  }
#pragma unroll
  for (int hd = 0; hd < 2; ++hd) {
    int d = hd * 16 + qq;
    vaOff[hd] = d * 64 + (((g ^ ((d ^ (d >> 2)) & 3))) << 4);
  }
#pragma unroll
  for (int F = 0; F < 2; ++F) {
    int row = wq * 16 + qq;
    bpOff[F] = row * 128 + (((2 * g + F) ^ (row & 7)) << 4);
  }
  const char* sBMr = sBM + (wq >> 2) * 4096;   // this wave-group's bm copy

#define STAGE(tt, dbi) do { \
    dma16(roleSrc + (size_t)(tt) * roleStride, roleDst + (dbi) * 4096); \
    dma16(pSrc0 + (size_t)(tt) * 128, sP + (dbi) * 16384 + wq * 2048); \
    dma16(pSrc1 + (size_t)(tt) * 128, sP + (dbi) * 16384 + wq * 2048 + 1024); \
  } while (0)

  f32x4 o00 = {}, o01 = {}, o10 = {}, o11 = {};
  float l0 = 0.f, l1 = 0.f;

  // prologue: stage bias_mask khq-quarter, 2 copies (waves 0-3 / 4-7), + tile 0
  {
    int p = wq & 3;
    dma16((const char*)bias_mask + (p >> 1) * 8192 + khq * 2048 + (p & 1) * 1024 + l * 16,
          sBM + (wq >> 2) * 4096 + p * 1024);
  }
  STAGE(0, 0);

#pragma unroll 1
  for (int t = 0; t < 16; ++t) {
    const int bi = t & 1;
    if (t < 15) {
      STAGE(t + 1, bi ^ 1);
      asm volatile("s_waitcnt vmcnt(3)" ::: "memory");
    } else {
      asm volatile("s_waitcnt vmcnt(0)" ::: "memory");
    }
    __builtin_amdgcn_s_barrier();
    __builtin_amdgcn_sched_barrier(0);

    const char* bP = sP + bi * 16384;
    f32x4 bp0 = *(const f32x4*)(bP + bpOff[0]);
    f32x4 bp1 = *(const f32x4*)(bP + bpOff[1]);
    const int bmOff = t * 128 + 32 * g;          // bytes: (t*32 + 8g)*4

    // ================= b = 0 =================
    {
      const char* bK = sK + bi * 4096;
      const char* bV = sV + bi * 4096;
      bf16x8 af0 = *(const bf16x8*)(bK + afOff[0]);
      bf16x8 af1 = *(const bf16x8*)(bK + afOff[1]);
      f32x4 z = {};
      f32x4 s0 = mfma32(af0, qf0, z);
      f32x4 s1 = mfma32(af1, qf0, z);
      f32x4 bm0 = *(const f32x4*)(sBMr + bmOff);
      f32x4 bm1 = *(const f32x4*)(sBMr + bmOff + 16);
#pragma unroll
      for (int r = 0; r < 4; ++r) {
        s0[r] += bp0[r] + bm0[r];
        s1[r] += bp1[r] + bm1[r];
      }
      U8 bu;
      {
        float p0 = __expf(s0[0]), p1 = __expf(s0[1]);
        float p2 = __expf(s0[2]), p3 = __expf(s0[3]);
        l0 += (p0 + p1) + (p2 + p3);
        bu.u[0] = cvt2bf(p0, p1); bu.u[1] = cvt2bf(p2, p3);
        p0 = __expf(s1[0]); p1 = __expf(s1[1]);
        p2 = __expf(s1[2]); p3 = __expf(s1[3]);
        l0 += (p0 + p1) + (p2 + p3);
        bu.u[2] = cvt2bf(p0, p1); bu.u[3] = cvt2bf(p2, p3);
      }
      bf16x8 va0 = *(const bf16x8*)(bV + vaOff[0]);
      bf16x8 va1 = *(const bf16x8*)(bV + vaOff[1]);
      o00 = mfma32(va0, bu.v, o00);
      o01 = mfma32(va1, bu.v, o01);
    }
    // ================= b = 1 =================
    {
      const char* bK = sK + bi * 4096 + 2048;
      const char* bV = sV + bi * 4096 + 2048;
      bf16x8 af0 = *(const bf16x8*)(bK + afOff[0]);
      bf16x8 af1 = *(const bf16x8*)(bK + afOff[1]);
      f32x4 z = {};
      f32x4 s0 = mfma32(af0, qf1, z);
      f32x4 s1 = mfma32(af1, qf1, z);
      f32x4 bm0 = *(const f32x4*)(sBMr + 2048 + bmOff);
      f32x4 bm1 = *(const f32x4*)(sBMr + 2048 + bmOff + 16);
#pragma unroll
      for (int r = 0; r < 4; ++r) {
        s0[r] += bp0[r] + bm0[r];
        s1[r] += bp1[r] + bm1[r];
      }
      U8 bu;
      {
        float p0 = __expf(s0[0]), p1 = __expf(s0[1]);
        float p2 = __expf(s0[2]), p3 = __expf(s0[3]);
        l1 += (p0 + p1) + (p2 + p3);
        bu.u[0] = cvt2bf(p0, p1); bu.u[1] = cvt2bf(p2, p3);
        p0 = __expf(s1[0]); p1 = __expf(s1[1]);
        p2 = __expf(s1[2]); p3 = __expf(s1[3]);
        l1 += (p0 + p1) + (p2 + p3);
        bu.u[2] = cvt2bf(p0, p1); bu.u[3] = cvt2bf(p2, p3);
      }
      bf16x8 va0 = *(const bf16x8*)(bV + vaOff[0]);
      bf16x8 va1 = *(const bf16x8*)(bV + vaOff[1]);
      o10 = mfma32(va0, bu.v, o10);
      o11 = mfma32(va1, bu.v, o11);
    }

    __builtin_amdgcn_sched_barrier(0);
    __builtin_amdgcn_s_barrier();
  }
#undef STAGE

  // ---- epilogue: per b: reduce l, transpose O^T via LDS, write partials ----
  l0 += __shfl_xor(l0, 16, 64);
  l0 += __shfl_xor(l0, 32, 64);
  l1 += __shfl_xor(l1, 16, 64);
  l1 += __shfl_xor(l1, 32, 64);
#pragma unroll
  for (int b = 0; b < 2; ++b) {
    f32x4 oa = b ? o10 : o00;
    f32x4 ob = b ? o11 : o01;
    float lr = b ? l1 : l0;
    __syncthreads();
    float* se = (float*)LDS + wq * 576;      // [16 q][36 d] per wave (8x2304B)
#pragma unroll
    for (int r = 0; r < 4; ++r) {
      se[qq * 36 + 4 * g + r]      = oa[r];   // d = 4g+r
      se[qq * 36 + 16 + 4 * g + r] = ob[r];   // d = 16+4g+r
    }
    if (g == 0) l_ws[khq * 32768 + b * 16384 + h * 2048 + q_glob] = lr;
    __syncthreads();
    const int qrow = l >> 2, pc = l & 3;
    const float* sr = (float*)LDS + wq * 576 + qrow * 36 + pc * 8;
    f32x4 x0 = *(const f32x4*)sr;
    f32x4 x1 = *(const f32x4*)(sr + 4);
    const int q_out = qt * 128 + wq * 16 + qrow;
    float* dst = O_ws + ((size_t)((khq * 2 + b) * HQ + q_out)) * NC + h * ND + pc * 8;
    *(f32x4*)dst = x0;
    *(f32x4*)(dst + 4) = x1;
  }
}

// ---------------- output projection (+ 4-way partial merge + gate) --------
// grid 256: bx&63 = Mblock, bx>>6 = Nblock. Head for column group ks is ks.
__global__ __launch_bounds__(256) void outproj_kernel(
    const float* __restrict__ O_ws, const float* __restrict__ l_ws,
    const float* __restrict__ g_ws, const float* __restrict__ Wo,
    const float* __restrict__ bo, float* __restrict__ out)
{
  const int bx = blockIdx.x;
  const int Mb = bx & 63, Nb = bx >> 6;
  const int Mbase = Mb * 64, Nbase = Nb * 64;
  __shared__ __align__(16) uint16_t smem2[4096];
  uint16_t* sA = smem2;
  uint16_t* sB = smem2 + 2048;
  const int tid = threadIdx.x;
  const int l = tid & 63, w = tid >> 6;
  const int qq = l & 15, g = l >> 4;
  const int row = tid >> 2, gp = tid & 3;
  const int m = Mbase + row, bb2 = m >> 11, qloc = m & 2047;
  f32x4 acc[4] = {};
  for (int ks = 0; ks < 8; ++ks) {
    const size_t lbase = (size_t)bb2 * 16384 + (size_t)ks * 2048 + qloc;
    const float inv = 1.f / (l_ws[lbase] + l_ws[32768 + lbase] +
                             l_ws[65536 + lbase] + l_ws[98304 + lbase]);
    const int col = ks * 32 + gp * 8;
    f32x4 a0 = {}, a1 = {};
#pragma unroll
    for (int kq = 0; kq < 4; ++kq) {
      const float* op = O_ws + ((size_t)((kq * 2 + bb2) * HQ + qloc)) * NC + col;
      f32x4 t0 = *(const f32x4*)op;
      f32x4 t1 = *(const f32x4*)(op + 4);
#pragma unroll
      for (int r = 0; r < 4; ++r) { a0[r] += t0[r]; a1[r] += t1[r]; }
    }
    const float* gpp = g_ws + ((size_t)(bb2 * HQ + qloc)) * NC + col;
    f32x4 g0 = *(const f32x4*)gpp;      f32x4 g1 = *(const f32x4*)(gpp + 4);
#pragma unroll
    for (int r = 0; r < 4; ++r) {
      a0[r] = a0[r] * inv * g0[r];
      a1[r] = a1[r] * inv * g1[r];
    }
    const float* wsrc = Wo + (size_t)(Nbase + row) * 256 + ks * 32 + gp * 8;
    f32x4 w0 = *(const f32x4*)wsrc;
    f32x4 w1 = *(const f32x4*)(wsrc + 4);
    U8 ua, uw;
    ua.u[0] = pack2bf(a0[0], a0[1]); ua.u[1] = pack2bf(a0[2], a0[3]);
    ua.u[2] = pack2bf(a1[0], a1[1]); ua.u[3] = pack2bf(a1[2], a1[3]);
    uw.u[0] = pack2bf(w0[0], w0[1]); uw.u[1] = pack2bf(w0[2], w0[3]);
    uw.u[2] = pack2bf(w1[0], w1[1]); uw.u[3] = pack2bf(w1[2], w1[3]);
    __syncthreads();
    *(bf16x8*)((char*)sA + swz64(row, gp)) = ua.v;
    *(bf16x8*)((char*)sB + swz64(row, gp)) = uw.v;
    __syncthreads();
    bf16x8 a = *(bf16x8*)((char*)sA + swz64(w * 16 + qq, g));
#pragma unroll
    for (int nf = 0; nf < 4; ++nf) {
      bf16x8 bb = *(bf16x8*)((char*)sB + swz64(nf * 16 + qq, g));
      acc[nf] = mfma32(a, bb, acc[nf]);
    }
  }
#pragma unroll
  for (int nf = 0; nf < 4; ++nf) {
    int n = Nbase + nf * 16 + qq;
    float bias = bo[n];
#pragma unroll
    for (int r = 0; r < 4; ++r) {
      int mm = Mbase + w * 16 + 4 * g + r;
      out[(size_t)mm * NC + n] = acc[nf][r] + bias;
    }
  }
}

extern "C" void kernel_launch(void* const* d_in, const int* in_sizes, int n_in,
                              void* d_out, int out_size, void* d_ws, size_t ws_size,
                              hipStream_t stream) {
  (void)in_sizes; (void)n_in; (void)out_size; (void)ws_size;
  const float* qx        = (const float*)d_in[0];
  const float* kvx       = (const float*)d_in[1];
  const float* bias_mask = (const float*)d_in[2];
  const float* bias_pair = (const float*)d_in[3];
  const float* Wq        = (const float*)d_in[4];
  const float* Wk        = (const float*)d_in[5];
  const float* Wv        = (const float*)d_in[6];
  const float* Wo        = (const float*)d_in[7];
  const float* bo        = (const float*)d_in[8];
  const float* Wg        = (const float*)d_in[9];
  const float* bg        = (const float*)d_in[10];

  char* ws = (char*)d_ws;
  uint16_t* q_p  = (uint16_t*)(ws);                       // 2 MB
  uint16_t* k_p  = (uint16_t*)(ws + (2u << 20));          // 2 MB
  uint16_t* v_p  = (uint16_t*)(ws + (4u << 20));          // 2 MB  [B,H,D,K]
  float*    g_ws = (float*)   (ws + (6u << 20));          // 4 MB
  float*    O_ws = (float*)   (ws + (10u << 20));         // 16 MB [khq,b,Q,HD] f32
  float*    l_ws = (float*)   (ws + (26u << 20));         // 512 KB [khq,b,h,Q]
  float* out = (float*)d_out;

  proj_kernel<<<dim3(256), dim3(256), 0, stream>>>(qx, kvx, Wq, Wk, Wv, Wg, bg,
                                                   q_p, k_p, v_p, g_ws);
  attn_kernel<<<dim3(512), dim3(512), 0, stream>>>(q_p, k_p, v_p, bias_mask,
                                                   bias_pair, O_ws, l_ws);
  outproj_kernel<<<dim3(256), dim3(256), 0, stream>>>(O_ws, l_ws, g_ws, Wo, bo, out);
}

// Round 18
// 67.174 us; speedup vs baseline: 1.4296x; 1.4296x over previous
//
#include <hip/hip_runtime.h>
#include <hip/hip_bf16.h>
#include <stdint.h>
#include <math.h>

typedef __attribute__((ext_vector_type(8))) short bf16x8;
typedef __attribute__((ext_vector_type(4))) float f32x4;

#define HQ 2048
#define HK 2048
#define NH 8
#define ND 32
#define NC 256

union U8 { uint32_t u[4]; bf16x8 v; };

__device__ __forceinline__ uint16_t f2bf(float f) {
  uint32_t u = __float_as_uint(f);
  u += 0x7FFFu + ((u >> 16) & 1u);   // RNE
  return (uint16_t)(u >> 16);
}
__device__ __forceinline__ uint32_t pack2bf(float a, float b) {
  return (uint32_t)f2bf(a) | ((uint32_t)f2bf(b) << 16);
}
// single-instruction RNE pack (v_cvt_pk_bf16_f32): lo=bf16(a), hi=bf16(b)
__device__ __forceinline__ uint32_t cvt2bf(float a, float b) {
  uint32_t r;
  asm("v_cvt_pk_bf16_f32 %0, %1, %2" : "=v"(r) : "v"(a), "v"(b));
  return r;
}
// 64B rows (32 bf16), 4 pieces of 16B
__device__ __forceinline__ int swz64(int row, int piece) {
  int s = (((row >> 3) & 1) << 1) | ((row >> 1) & 1);
  return row * 64 + ((piece ^ s) << 4);
}
__device__ __forceinline__ f32x4 mfma32(bf16x8 a, bf16x8 b, f32x4 c) {
  return __builtin_amdgcn_mfma_f32_16x16x32_bf16(a, b, c, 0, 0, 0);
}
// async global->LDS DMA, 16B per lane; dst wave-uniform (HW: dst+lane*16)
__device__ __forceinline__ void dma16(const void* g, void* l) {
  __builtin_amdgcn_global_load_lds(
      (const __attribute__((address_space(1))) uint32_t*)g,
      (__attribute__((address_space(3))) uint32_t*)l, 16, 0, 0);
}

// ---------------- projections: q,k,v,g -----------------------------------
// grid 256: bx&63 = Mblock(64 rows), bx>>6 = proj id. Block computes ALL 256
// output cols (X staged ONCE -> X traffic 48->12MB vs old 4-Nb split).
// NOTE: V-transpose sub-tile loop MUST be fully unrolled - runtime-indexed
// acc[] would spill the whole accumulator to scratch (R17: 95MB writes).
__global__ __launch_bounds__(256) void proj_kernel(
    const float* __restrict__ qx, const float* __restrict__ kvx,
    const float* __restrict__ Wq, const float* __restrict__ Wk,
    const float* __restrict__ Wv, const float* __restrict__ Wg,
    const float* __restrict__ bg,
    uint16_t* __restrict__ q_p, uint16_t* __restrict__ k_p,
    uint16_t* __restrict__ v_p, float* __restrict__ g_ws)
{
  const int bx = blockIdx.x;
  const int Mb = bx & 63, p = bx >> 6;
  const int Mbase = Mb * 64;
  const float* X = (p == 0 || p == 3) ? qx : kvx;
  const float* W = (p == 0) ? Wq : (p == 1) ? Wk : (p == 2) ? Wv : Wg;

  __shared__ __align__(16) uint16_t smem[10240]; // sX 64x32 (4KB) | sW 256x32 (16KB)
  uint16_t* sX = smem;
  uint16_t* sW = smem + 2048;

  const int tid = threadIdx.x;
  const int l = tid & 63, w = tid >> 6;
  const int qq = l & 15, g = l >> 4;
  const int row = tid >> 2, gp = tid & 3;

  f32x4 acc[16] = {};

  for (int ks = 0; ks < 8; ++ks) {
    const float* xs = X + (size_t)(Mbase + row) * 256 + ks * 32 + gp * 8;
    f32x4 x0 = *(const f32x4*)xs;
    f32x4 x1 = *(const f32x4*)(xs + 4);
    f32x4 wv[4][2];
#pragma unroll
    for (int j = 0; j < 4; ++j) {
      const float* ws_ = W + (size_t)(j * 64 + row) * 256 + ks * 32 + gp * 8;
      wv[j][0] = *(const f32x4*)ws_;
      wv[j][1] = *(const f32x4*)(ws_ + 4);
    }
    __syncthreads();
    {
      U8 ux;
      ux.u[0] = pack2bf(x0[0], x0[1]); ux.u[1] = pack2bf(x0[2], x0[3]);
      ux.u[2] = pack2bf(x1[0], x1[1]); ux.u[3] = pack2bf(x1[2], x1[3]);
      *(bf16x8*)((char*)sX + swz64(row, gp)) = ux.v;
    }
#pragma unroll
    for (int j = 0; j < 4; ++j) {
      U8 uw;
      uw.u[0] = pack2bf(wv[j][0][0], wv[j][0][1]);
      uw.u[1] = pack2bf(wv[j][0][2], wv[j][0][3]);
      uw.u[2] = pack2bf(wv[j][1][0], wv[j][1][1]);
      uw.u[3] = pack2bf(wv[j][1][2], wv[j][1][3]);
      *(bf16x8*)((char*)sW + swz64(j * 64 + row, gp)) = uw.v;
    }
    __syncthreads();
    bf16x8 a = *(bf16x8*)((char*)sX + swz64(w * 16 + qq, g));
#pragma unroll
    for (int nf = 0; nf < 16; ++nf) {
      bf16x8 bb = *(bf16x8*)((char*)sW + swz64(nf * 16 + qq, g));
      acc[nf] = mfma32(a, bb, acc[nf]);
    }
  }

  if (p == 2) {
    // transpose epilogue -> v_p[B,H,D,K], 4 sequential 64x64 sub-tiles.
    // FULLY UNROLLED so acc indices stay compile-time constant (rule #20).
    const int bb_ = Mbase >> 11;
#pragma unroll
    for (int nb = 0; nb < 4; ++nb) {
      __syncthreads();
#pragma unroll
      for (int nf2 = 0; nf2 < 4; ++nf2) {
        int n_loc = nf2 * 16 + qq;
#pragma unroll
        for (int r = 0; r < 4; ++r) {
          int m_loc = w * 16 + 4 * g + r;
          int byte = n_loc * 128 + ((((m_loc >> 3) ^ (n_loc & 7)) << 4)) + (m_loc & 7) * 2;
          *(uint16_t*)((char*)smem + byte) = f2bf(acc[nb * 4 + nf2][r]);
        }
      }
      __syncthreads();
      const int n_loc = tid >> 2, mp = tid & 3;
      const int ng = nb * 64 + n_loc;
      const int hh = ng >> 5, dd = ng & 31;
#pragma unroll
      for (int jj = 0; jj < 2; ++jj) {
        int piece = mp * 2 + jj;
        bf16x8 vv = *(bf16x8*)((char*)smem + n_loc * 128 + ((piece ^ (n_loc & 7)) << 4));
        int seq = (Mbase & 2047) + piece * 8;
        *(bf16x8*)(v_p + ((size_t)(bb_ * NH + hh) * ND + dd) * (size_t)HK + seq) = vv;
      }
    }
    return;
  }

#pragma unroll
  for (int nf = 0; nf < 16; ++nf) {
    int n = nf * 16 + qq;
#pragma unroll
    for (int r = 0; r < 4; ++r) {
      int m = Mbase + w * 16 + 4 * g + r;
      float val = acc[nf][r];
      if (p == 0) {
        val *= 0.17677669529663687f; // 1/sqrt(32)
        int bb_ = m >> 11, seq = m & 2047, hh = n >> 5, dd = n & 31;
        q_p[((size_t)(bb_ * NH + hh) * HQ + seq) * ND + dd] = f2bf(val);
      } else if (p == 1) {
        int bb_ = m >> 11, seq = m & 2047, hh = n >> 5, dd = n & 31;
        k_p[((size_t)(bb_ * NH + hh) * HK + seq) * ND + dd] = f2bf(val);
      } else { // p == 3 : gate
        g_ws[(size_t)m * NC + n] = 1.f / (1.f + __expf(-(val + bg[n])));
      }
    }
  }
}

// ---------------- fused attention -----------------------------------------
// grid 512 x 512 thr: bx&3=khq (K quarter, 512 k), (bx>>2)&7=h, bx>>5=qt
// (128 q rows). 8 waves; wave wq owns q-rows qt*128+wq*16..+15, BOTH batches.
// k-tile 32 -> 16 iters. Per iter per wave exactly 3 DMAs -> counted vmcnt(3).
// LDS 56KB -> 2 blocks/CU. v_cvt_pk_bf16_f32 packing.  (R15-proven body.)
// Unnormalized softmax; 4-way K-split partials merged in outproj.
__global__ __launch_bounds__(512, 4) void attn_kernel(
    const uint16_t* __restrict__ q_p, const uint16_t* __restrict__ k_p,
    const uint16_t* __restrict__ v_p, const float* __restrict__ bias_mask,
    const float* __restrict__ bias_pair,
    float* __restrict__ O_ws, float* __restrict__ l_ws)
{
  const int bx = blockIdx.x;
  const int khq = bx & 3, h = (bx >> 2) & 7, qt = bx >> 5;

  __shared__ __align__(16) char LDS[57344];    // 56 KB
  char* sK = LDS;             // 2buf x 2b x 2KB = 8KB
  char* sV = LDS + 8192;      // 2buf x 2b x 2KB = 8KB
  char* sP = LDS + 16384;     // 2buf x 16KB     = 32KB
  char* sBM = LDS + 49152;    // 2 copies x (2b x 2KB) = 8KB

  const int tid = threadIdx.x;
  const int l = tid & 63, wq = tid >> 6;       // wq 0..7
  const int qq = l & 15, g = l >> 4;
  const int q_glob = qt * 128 + wq * 16 + qq;

  // Q B-fragments for both batches (hoisted)
  bf16x8 qf0 = *(const bf16x8*)(q_p + ((size_t)h * HQ + q_glob) * ND + g * 8);
  bf16x8 qf1 = *(const bf16x8*)(q_p + ((size_t)(NH + h) * HQ + q_glob) * ND + g * 8);

  // ---- role staging: waves 0-3 stage K, waves 4-7 stage V ----
  const int rw = wq & 3;                 // role sub-index
  const int bsel = rw >> 1, hsel = rw & 1;
  const char* roleSrc;
  int roleStride;
  char* roleDst;                          // + dbi*4096 at use
  if (wq < 4) {
    int B = hsel * 1024 + l * 16;
    int Lr = B >> 7, cpos = l & 7;
    int hp = cpos ^ (Lr & 7);
    int half = hp >> 2, pc = hp & 3;
    int s = Lr * 2 + half, F = s >> 4, qs = s & 15;
    int krow = 8 * (qs >> 2) + (qs & 3) + 4 * F;
    roleSrc = (const char*)k_p + (size_t)(bsel * NH + h) * HK * ND * 2
              + khq * 32768 + krow * 64 + pc * 16;
    roleStride = 2048;
    roleDst = sK + bsel * 2048 + hsel * 1024;
  } else {
    int B = hsel * 1024 + l * 16;
    int d = B >> 6, cpos = l & 3;
    int gs = cpos ^ ((d ^ (d >> 2)) & 3);
    roleSrc = (const char*)v_p + (size_t)(bsel * NH + h) * ND * (size_t)HK * 2
              + khq * 1024 + (size_t)d * (HK * 2) + gs * 16;
    roleStride = 64;
    roleDst = sV + bsel * 2048 + hsel * 1024;
  }
  // bias_pair: each wave stages its own 16 q-rows x 128B = 2 x 1KB dma.
  const char* pSrc0; const char* pSrc1;
  {
    const char* bpBlk = (const char*)bias_pair
        + ((size_t)h * HQ + qt * 128) * (size_t)HK * 4 + khq * 2048;
#define BP_SRC(jj) ({ int row = wq * 16 + (jj) * 8 + (l >> 3); \
                      int gs = (l & 7) ^ (row & 7); \
                      bpBlk + (size_t)row * (HK * 4) + gs * 16; })
    pSrc0 = BP_SRC(0); pSrc1 = BP_SRC(1);
#undef BP_SRC
  }

  // ---- reader byte offsets (loop-invariant; R11-proven) ----
  int afOff[2], vaOff[2], bpOff[2];
#pragma unroll
  for (int F = 0; F < 2; ++F) {
    int Lr = 8 * F + (qq >> 1);
    afOff[F] = Lr * 128 + ((((qq & 1) * 4 + g) ^ (Lr & 7)) << 4);
  }
#pragma unroll
  for (int hd = 0; hd < 2; ++hd) {
    int d = hd * 16 + qq;
    vaOff[hd] = d * 64 + (((g ^ ((d ^ (d >> 2)) & 3))) << 4);
  }
#pragma unroll
  for (int F = 0; F < 2; ++F) {
    int row = wq * 16 + qq;
    bpOff[F] = row * 128 + (((2 * g + F) ^ (row & 7)) << 4);
  }
  const char* sBMr = sBM + (wq >> 2) * 4096;   // this wave-group's bm copy

#define STAGE(tt, dbi) do { \
    dma16(roleSrc + (size_t)(tt) * roleStride, roleDst + (dbi) * 4096); \
    dma16(pSrc0 + (size_t)(tt) * 128, sP + (dbi) * 16384 + wq * 2048); \
    dma16(pSrc1 + (size_t)(tt) * 128, sP + (dbi) * 16384 + wq * 2048 + 1024); \
  } while (0)

  f32x4 o00 = {}, o01 = {}, o10 = {}, o11 = {};
  float l0 = 0.f, l1 = 0.f;

  // prologue: stage bias_mask khq-quarter, 2 copies (waves 0-3 / 4-7), + tile 0
  {
    int p = wq & 3;
    dma16((const char*)bias_mask + (p >> 1) * 8192 + khq * 2048 + (p & 1) * 1024 + l * 16,
          sBM + (wq >> 2) * 4096 + p * 1024);
  }
  STAGE(0, 0);

#pragma unroll 1
  for (int t = 0; t < 16; ++t) {
    const int bi = t & 1;
    if (t < 15) {
      STAGE(t + 1, bi ^ 1);
      asm volatile("s_waitcnt vmcnt(3)" ::: "memory");
    } else {
      asm volatile("s_waitcnt vmcnt(0)" ::: "memory");
    }
    __builtin_amdgcn_s_barrier();
    __builtin_amdgcn_sched_barrier(0);

    const char* bP = sP + bi * 16384;
    f32x4 bp0 = *(const f32x4*)(bP + bpOff[0]);
    f32x4 bp1 = *(const f32x4*)(bP + bpOff[1]);
    const int bmOff = t * 128 + 32 * g;          // bytes: (t*32 + 8g)*4

    // ================= b = 0 =================
    {
      const char* bK = sK + bi * 4096;
      const char* bV = sV + bi * 4096;
      bf16x8 af0 = *(const bf16x8*)(bK + afOff[0]);
      bf16x8 af1 = *(const bf16x8*)(bK + afOff[1]);
      f32x4 z = {};
      f32x4 s0 = mfma32(af0, qf0, z);
      f32x4 s1 = mfma32(af1, qf0, z);
      f32x4 bm0 = *(const f32x4*)(sBMr + bmOff);
      f32x4 bm1 = *(const f32x4*)(sBMr + bmOff + 16);
#pragma unroll
      for (int r = 0; r < 4; ++r) {
        s0[r] += bp0[r] + bm0[r];
        s1[r] += bp1[r] + bm1[r];
      }
      U8 bu;
      {
        float p0 = __expf(s0[0]), p1 = __expf(s0[1]);
        float p2 = __expf(s0[2]), p3 = __expf(s0[3]);
        l0 += (p0 + p1) + (p2 + p3);
        bu.u[0] = cvt2bf(p0, p1); bu.u[1] = cvt2bf(p2, p3);
        p0 = __expf(s1[0]); p1 = __expf(s1[1]);
        p2 = __expf(s1[2]); p3 = __expf(s1[3]);
        l0 += (p0 + p1) + (p2 + p3);
        bu.u[2] = cvt2bf(p0, p1); bu.u[3] = cvt2bf(p2, p3);
      }
      bf16x8 va0 = *(const bf16x8*)(bV + vaOff[0]);
      bf16x8 va1 = *(const bf16x8*)(bV + vaOff[1]);
      o00 = mfma32(va0, bu.v, o00);
      o01 = mfma32(va1, bu.v, o01);
    }
    // ================= b = 1 =================
    {
      const char* bK = sK + bi * 4096 + 2048;
      const char* bV = sV + bi * 4096 + 2048;
      bf16x8 af0 = *(const bf16x8*)(bK + afOff[0]);
      bf16x8 af1 = *(const bf16x8*)(bK + afOff[1]);
      f32x4 z = {};
      f32x4 s0 = mfma32(af0, qf1, z);
      f32x4 s1 = mfma32(af1, qf1, z);
      f32x4 bm0 = *(const f32x4*)(sBMr + 2048 + bmOff);
      f32x4 bm1 = *(const f32x4*)(sBMr + 2048 + bmOff + 16);
#pragma unroll
      for (int r = 0; r < 4; ++r) {
        s0[r] += bp0[r] + bm0[r];
        s1[r] += bp1[r] + bm1[r];
      }
      U8 bu;
      {
        float p0 = __expf(s0[0]), p1 = __expf(s0[1]);
        float p2 = __expf(s0[2]), p3 = __expf(s0[3]);
        l1 += (p0 + p1) + (p2 + p3);
        bu.u[0] = cvt2bf(p0, p1); bu.u[1] = cvt2bf(p2, p3);
        p0 = __expf(s1[0]); p1 = __expf(s1[1]);
        p2 = __expf(s1[2]); p3 = __expf(s1[3]);
        l1 += (p0 + p1) + (p2 + p3);
        bu.u[2] = cvt2bf(p0, p1); bu.u[3] = cvt2bf(p2, p3);
      }
      bf16x8 va0 = *(const bf16x8*)(bV + vaOff[0]);
      bf16x8 va1 = *(const bf16x8*)(bV + vaOff[1]);
      o10 = mfma32(va0, bu.v, o10);
      o11 = mfma32(va1, bu.v, o11);
    }

    __builtin_amdgcn_sched_barrier(0);
    __builtin_amdgcn_s_barrier();
  }
#undef STAGE

  // ---- epilogue: per b: reduce l, transpose O^T via LDS, write partials ----
  l0 += __shfl_xor(l0, 16, 64);
  l0 += __shfl_xor(l0, 32, 64);
  l1 += __shfl_xor(l1, 16, 64);
  l1 += __shfl_xor(l1, 32, 64);
#pragma unroll
  for (int b = 0; b < 2; ++b) {
    f32x4 oa = b ? o10 : o00;
    f32x4 ob = b ? o11 : o01;
    float lr = b ? l1 : l0;
    __syncthreads();
    float* se = (float*)LDS + wq * 576;      // [16 q][36 d] per wave (8x2304B)
#pragma unroll
    for (int r = 0; r < 4; ++r) {
      se[qq * 36 + 4 * g + r]      = oa[r];   // d = 4g+r
      se[qq * 36 + 16 + 4 * g + r] = ob[r];   // d = 16+4g+r
    }
    if (g == 0) l_ws[khq * 32768 + b * 16384 + h * 2048 + q_glob] = lr;
    __syncthreads();
    const int qrow = l >> 2, pc = l & 3;
    const float* sr = (float*)LDS + wq * 576 + qrow * 36 + pc * 8;
    f32x4 x0 = *(const f32x4*)sr;
    f32x4 x1 = *(const f32x4*)(sr + 4);
    const int q_out = qt * 128 + wq * 16 + qrow;
    float* dst = O_ws + ((size_t)((khq * 2 + b) * HQ + q_out)) * NC + h * ND + pc * 8;
    *(f32x4*)dst = x0;
    *(f32x4*)(dst + 4) = x1;
  }
}

// ---------------- output projection (+ 4-way partial merge + gate) --------
// grid 256: bx&63 = Mblock, bx>>6 = Nblock. Head for column group ks is ks.
__global__ __launch_bounds__(256) void outproj_kernel(
    const float* __restrict__ O_ws, const float* __restrict__ l_ws,
    const float* __restrict__ g_ws, const float* __restrict__ Wo,
    const float* __restrict__ bo, float* __restrict__ out)
{
  const int bx = blockIdx.x;
  const int Mb = bx & 63, Nb = bx >> 6;
  const int Mbase = Mb * 64, Nbase = Nb * 64;
  __shared__ __align__(16) uint16_t smem2[4096];
  uint16_t* sA = smem2;
  uint16_t* sB = smem2 + 2048;
  const int tid = threadIdx.x;
  const int l = tid & 63, w = tid >> 6;
  const int qq = l & 15, g = l >> 4;
  const int row = tid >> 2, gp = tid & 3;
  const int m = Mbase + row, bb2 = m >> 11, qloc = m & 2047;
  f32x4 acc[4] = {};
  for (int ks = 0; ks < 8; ++ks) {
    const size_t lbase = (size_t)bb2 * 16384 + (size_t)ks * 2048 + qloc;
    const float inv = 1.f / (l_ws[lbase] + l_ws[32768 + lbase] +
                             l_ws[65536 + lbase] + l_ws[98304 + lbase]);
    const int col = ks * 32 + gp * 8;
    f32x4 a0 = {}, a1 = {};
#pragma unroll
    for (int kq = 0; kq < 4; ++kq) {
      const float* op = O_ws + ((size_t)((kq * 2 + bb2) * HQ + qloc)) * NC + col;
      f32x4 t0 = *(const f32x4*)op;
      f32x4 t1 = *(const f32x4*)(op + 4);
#pragma unroll
      for (int r = 0; r < 4; ++r) { a0[r] += t0[r]; a1[r] += t1[r]; }
    }
    const float* gpp = g_ws + ((size_t)(bb2 * HQ + qloc)) * NC + col;
    f32x4 g0 = *(const f32x4*)gpp;      f32x4 g1 = *(const f32x4*)(gpp + 4);
#pragma unroll
    for (int r = 0; r < 4; ++r) {
      a0[r] = a0[r] * inv * g0[r];
      a1[r] = a1[r] * inv * g1[r];
    }
    const float* wsrc = Wo + (size_t)(Nbase + row) * 256 + ks * 32 + gp * 8;
    f32x4 w0 = *(const f32x4*)wsrc;
    f32x4 w1 = *(const f32x4*)(wsrc + 4);
    U8 ua, uw;
    ua.u[0] = pack2bf(a0[0], a0[1]); ua.u[1] = pack2bf(a0[2], a0[3]);
    ua.u[2] = pack2bf(a1[0], a1[1]); ua.u[3] = pack2bf(a1[2], a1[3]);
    uw.u[0] = pack2bf(w0[0], w0[1]); uw.u[1] = pack2bf(w0[2], w0[3]);
    uw.u[2] = pack2bf(w1[0], w1[1]); uw.u[3] = pack2bf(w1[2], w1[3]);
    __syncthreads();
    *(bf16x8*)((char*)sA + swz64(row, gp)) = ua.v;
    *(bf16x8*)((char*)sB + swz64(row, gp)) = uw.v;
    __syncthreads();
    bf16x8 a = *(bf16x8*)((char*)sA + swz64(w * 16 + qq, g));
#pragma unroll
    for (int nf = 0; nf < 4; ++nf) {
      bf16x8 bb = *(bf16x8*)((char*)sB + swz64(nf * 16 + qq, g));
      acc[nf] = mfma32(a, bb, acc[nf]);
    }
  }
#pragma unroll
  for (int nf = 0; nf < 4; ++nf) {
    int n = Nbase + nf * 16 + qq;
    float bias = bo[n];
#pragma unroll
    for (int r = 0; r < 4; ++r) {
      int mm = Mbase + w * 16 + 4 * g + r;
      out[(size_t)mm * NC + n] = acc[nf][r] + bias;
    }
  }
}

extern "C" void kernel_launch(void* const* d_in, const int* in_sizes, int n_in,
                              void* d_out, int out_size, void* d_ws, size_t ws_size,
                              hipStream_t stream) {
  (void)in_sizes; (void)n_in; (void)out_size; (void)ws_size;
  const float* qx        = (const float*)d_in[0];
  const float* kvx       = (const float*)d_in[1];
  const float* bias_mask = (const float*)d_in[2];
  const float* bias_pair = (const float*)d_in[3];
  const float* Wq        = (const float*)d_in[4];
  const float* Wk        = (const float*)d_in[5];
  const float* Wv        = (const float*)d_in[6];
  const float* Wo        = (const float*)d_in[7];
  const float* bo        = (const float*)d_in[8];
  const float* Wg        = (const float*)d_in[9];
  const float* bg        = (const float*)d_in[10];

  char* ws = (char*)d_ws;
  uint16_t* q_p  = (uint16_t*)(ws);                       // 2 MB
  uint16_t* k_p  = (uint16_t*)(ws + (2u << 20));          // 2 MB
  uint16_t* v_p  = (uint16_t*)(ws + (4u << 20));          // 2 MB  [B,H,D,K]
  float*    g_ws = (float*)   (ws + (6u << 20));          // 4 MB
  float*    O_ws = (float*)   (ws + (10u << 20));         // 16 MB [khq,b,Q,HD] f32
  float*    l_ws = (float*)   (ws + (26u << 20));         // 512 KB [khq,b,h,Q]
  float* out = (float*)d_out;

  proj_kernel<<<dim3(256), dim3(256), 0, stream>>>(qx, kvx, Wq, Wk, Wv, Wg, bg,
                                                   q_p, k_p, v_p, g_ws);
  attn_kernel<<<dim3(512), dim3(512), 0, stream>>>(q_p, k_p, v_p, bias_mask,
                                                   bias_pair, O_ws, l_ws);
  outproj_kernel<<<dim3(256), dim3(256), 0, stream>>>(O_ws, l_ws, g_ws, Wo, bo, out);
}

// Round 19
// 54.106 us; speedup vs baseline: 1.7748x; 1.2415x over previous
//
#include <hip/hip_runtime.h>
#include <hip/hip_bf16.h>
#include <stdint.h>
#include <math.h>

typedef __attribute__((ext_vector_type(8))) short bf16x8;
typedef __attribute__((ext_vector_type(4))) float f32x4;

#define HQ 2048
#define HK 2048
#define NH 8
#define ND 32
#define NC 256

union U8 { uint32_t u[4]; bf16x8 v; };

__device__ __forceinline__ uint16_t f2bf(float f) {
  uint32_t u = __float_as_uint(f);
  u += 0x7FFFu + ((u >> 16) & 1u);   // RNE
  return (uint16_t)(u >> 16);
}
__device__ __forceinline__ uint32_t pack2bf(float a, float b) {
  return (uint32_t)f2bf(a) | ((uint32_t)f2bf(b) << 16);
}
// single-instruction RNE pack (v_cvt_pk_bf16_f32): lo=bf16(a), hi=bf16(b)
__device__ __forceinline__ uint32_t cvt2bf(float a, float b) {
  uint32_t r;
  asm("v_cvt_pk_bf16_f32 %0, %1, %2" : "=v"(r) : "v"(a), "v"(b));
  return r;
}
// 64B rows (32 bf16), 4 pieces of 16B
__device__ __forceinline__ int swz64(int row, int piece) {
  int s = (((row >> 3) & 1) << 1) | ((row >> 1) & 1);
  return row * 64 + ((piece ^ s) << 4);
}
__device__ __forceinline__ f32x4 mfma32(bf16x8 a, bf16x8 b, f32x4 c) {
  return __builtin_amdgcn_mfma_f32_16x16x32_bf16(a, b, c, 0, 0, 0);
}
// async global->LDS DMA, 16B per lane; dst wave-uniform (HW: dst+lane*16)
__device__ __forceinline__ void dma16(const void* g, void* l) {
  __builtin_amdgcn_global_load_lds(
      (const __attribute__((address_space(1))) uint32_t*)g,
      (__attribute__((address_space(3))) uint32_t*)l, 16, 0, 0);
}

// ---------------- projections: q,k,v,g -----------------------------------
// grid 1024: bx&63 = Mblock(64), (bx>>6)&3 = Nblock(4), bx>>8 = proj id
// (4 blocks/CU; X re-reads across Nb are L2 hits - not HBM traffic.)
__global__ __launch_bounds__(256) void proj_kernel(
    const float* __restrict__ qx, const float* __restrict__ kvx,
    const float* __restrict__ Wq, const float* __restrict__ Wk,
    const float* __restrict__ Wv, const float* __restrict__ Wg,
    const float* __restrict__ bg,
    uint16_t* __restrict__ q_p, uint16_t* __restrict__ k_p,
    uint16_t* __restrict__ v_p, float* __restrict__ g_ws)
{
  const int bx = blockIdx.x;
  const int Mb = bx & 63, Nb = (bx >> 6) & 3, p = bx >> 8;
  const int Mbase = Mb * 64, Nbase = Nb * 64;
  const float* X = (p == 0 || p == 3) ? qx : kvx;
  const float* W = (p == 0) ? Wq : (p == 1) ? Wk : (p == 2) ? Wv : Wg;

  __shared__ __align__(16) uint16_t smem[4096]; // 8KB: X tile | W tile
  uint16_t* sX = smem;
  uint16_t* sW = smem + 2048;

  const int tid = threadIdx.x;
  const int l = tid & 63, w = tid >> 6;
  const int qq = l & 15, g = l >> 4;
  const int row = tid >> 2, gp = tid & 3;

  f32x4 acc[4] = {};

  for (int ks = 0; ks < 8; ++ks) {
    const float* xs = X + (size_t)(Mbase + row) * 256 + ks * 32 + gp * 8;
    f32x4 x0 = *(const f32x4*)xs;
    f32x4 x1 = *(const f32x4*)(xs + 4);
    const float* ws_ = W + (size_t)(Nbase + row) * 256 + ks * 32 + gp * 8;
    f32x4 w0 = *(const f32x4*)ws_;
    f32x4 w1 = *(const f32x4*)(ws_ + 4);
    U8 ux, uw;
    ux.u[0] = pack2bf(x0[0], x0[1]); ux.u[1] = pack2bf(x0[2], x0[3]);
    ux.u[2] = pack2bf(x1[0], x1[1]); ux.u[3] = pack2bf(x1[2], x1[3]);
    uw.u[0] = pack2bf(w0[0], w0[1]); uw.u[1] = pack2bf(w0[2], w0[3]);
    uw.u[2] = pack2bf(w1[0], w1[1]); uw.u[3] = pack2bf(w1[2], w1[3]);
    __syncthreads();
    *(bf16x8*)((char*)sX + swz64(row, gp)) = ux.v;
    *(bf16x8*)((char*)sW + swz64(row, gp)) = uw.v;
    __syncthreads();
    bf16x8 a = *(bf16x8*)((char*)sX + swz64(w * 16 + qq, g));
#pragma unroll
    for (int nf = 0; nf < 4; ++nf) {
      bf16x8 bb = *(bf16x8*)((char*)sW + swz64(nf * 16 + qq, g));
      acc[nf] = mfma32(a, bb, acc[nf]);
    }
  }

  if (p == 2) {
    // transpose epilogue -> v_p[B,H,D,K]
    __syncthreads();
#pragma unroll
    for (int nf = 0; nf < 4; ++nf) {
      int n_loc = nf * 16 + qq;
#pragma unroll
      for (int r = 0; r < 4; ++r) {
        int m_loc = w * 16 + 4 * g + r;
        int byte = n_loc * 128 + ((((m_loc >> 3) ^ (n_loc & 7)) << 4)) + (m_loc & 7) * 2;
        *(uint16_t*)((char*)smem + byte) = f2bf(acc[nf][r]);
      }
    }
    __syncthreads();
    const int n_loc = tid >> 2, mp = tid & 3;
    const int ng = Nbase + n_loc;
    const int hh = ng >> 5, dd = ng & 31;
    const int bb_ = Mbase >> 11;
#pragma unroll
    for (int jj = 0; jj < 2; ++jj) {
      int piece = mp * 2 + jj;
      bf16x8 vv = *(bf16x8*)((char*)smem + n_loc * 128 + ((piece ^ (n_loc & 7)) << 4));
      int seq = (Mbase & 2047) + piece * 8;
      *(bf16x8*)(v_p + ((size_t)(bb_ * NH + hh) * ND + dd) * (size_t)HK + seq) = vv;
    }
    return;
  }

#pragma unroll
  for (int nf = 0; nf < 4; ++nf) {
    int n = Nbase + nf * 16 + qq;
#pragma unroll
    for (int r = 0; r < 4; ++r) {
      int m = Mbase + w * 16 + 4 * g + r;
      float val = acc[nf][r];
      if (p == 0) {
        val *= 0.17677669529663687f; // 1/sqrt(32)
        int bb_ = m >> 11, seq = m & 2047, hh = n >> 5, dd = n & 31;
        q_p[((size_t)(bb_ * NH + hh) * HQ + seq) * ND + dd] = f2bf(val);
      } else if (p == 1) {
        int bb_ = m >> 11, seq = m & 2047, hh = n >> 5, dd = n & 31;
        k_p[((size_t)(bb_ * NH + hh) * HK + seq) * ND + dd] = f2bf(val);
      } else { // p == 3 : gate
        g_ws[(size_t)m * NC + n] = 1.f / (1.f + __expf(-(val + bg[n])));
      }
    }
  }
}

// ---------------- fused attention -----------------------------------------
// grid 512 x 512 thr: bx&3=khq (K quarter, 512 k), (bx>>2)&7=h, bx>>5=qt
// (128 q rows). 8 waves; wave wq owns q-rows qt*128+wq*16..+15, BOTH batches.
// k-tile 32 -> 16 iters. Per iter per wave exactly 3 DMAs -> counted vmcnt(3).
// LDS 56KB -> 2 blocks/CU. v_cvt_pk_bf16_f32 packing.
// Unnormalized softmax; 4-way K-split partials merged in outproj.
__global__ __launch_bounds__(512, 4) void attn_kernel(
    const uint16_t* __restrict__ q_p, const uint16_t* __restrict__ k_p,
    const uint16_t* __restrict__ v_p, const float* __restrict__ bias_mask,
    const float* __restrict__ bias_pair,
    float* __restrict__ O_ws, float* __restrict__ l_ws)
{
  const int bx = blockIdx.x;
  const int khq = bx & 3, h = (bx >> 2) & 7, qt = bx >> 5;

  __shared__ __align__(16) char LDS[57344];    // 56 KB
  char* sK = LDS;             // 2buf x 2b x 2KB = 8KB
  char* sV = LDS + 8192;      // 2buf x 2b x 2KB = 8KB
  char* sP = LDS + 16384;     // 2buf x 16KB     = 32KB
  char* sBM = LDS + 49152;    // 2 copies x (2b x 2KB) = 8KB

  const int tid = threadIdx.x;
  const int l = tid & 63, wq = tid >> 6;       // wq 0..7
  const int qq = l & 15, g = l >> 4;
  const int q_glob = qt * 128 + wq * 16 + qq;

  // Q B-fragments for both batches (hoisted)
  bf16x8 qf0 = *(const bf16x8*)(q_p + ((size_t)h * HQ + q_glob) * ND + g * 8);
  bf16x8 qf1 = *(const bf16x8*)(q_p + ((size_t)(NH + h) * HQ + q_glob) * ND + g * 8);

  // ---- role staging: waves 0-3 stage K, waves 4-7 stage V ----
  const int rw = wq & 3;                 // role sub-index
  const int bsel = rw >> 1, hsel = rw & 1;
  const char* roleSrc;
  int roleStride;
  char* roleDst;                          // + dbi*4096 at use
  if (wq < 4) {
    int B = hsel * 1024 + l * 16;
    int Lr = B >> 7, cpos = l & 7;
    int hp = cpos ^ (Lr & 7);
    int half = hp >> 2, pc = hp & 3;
    int s = Lr * 2 + half, F = s >> 4, qs = s & 15;
    int krow = 8 * (qs >> 2) + (qs & 3) + 4 * F;
    roleSrc = (const char*)k_p + (size_t)(bsel * NH + h) * HK * ND * 2
              + khq * 32768 + krow * 64 + pc * 16;
    roleStride = 2048;
    roleDst = sK + bsel * 2048 + hsel * 1024;
  } else {
    int B = hsel * 1024 + l * 16;
    int d = B >> 6, cpos = l & 3;
    int gs = cpos ^ ((d ^ (d >> 2)) & 3);
    roleSrc = (const char*)v_p + (size_t)(bsel * NH + h) * ND * (size_t)HK * 2
              + khq * 1024 + (size_t)d * (HK * 2) + gs * 16;
    roleStride = 64;
    roleDst = sV + bsel * 2048 + hsel * 1024;
  }
  // bias_pair: each wave stages its own 16 q-rows x 128B = 2 x 1KB dma.
  const char* pSrc0; const char* pSrc1;
  {
    const char* bpBlk = (const char*)bias_pair
        + ((size_t)h * HQ + qt * 128) * (size_t)HK * 4 + khq * 2048;
#define BP_SRC(jj) ({ int row = wq * 16 + (jj) * 8 + (l >> 3); \
                      int gs = (l & 7) ^ (row & 7); \
                      bpBlk + (size_t)row * (HK * 4) + gs * 16; })
    pSrc0 = BP_SRC(0); pSrc1 = BP_SRC(1);
#undef BP_SRC
  }

  // ---- reader byte offsets (loop-invariant) ----
  int afOff[2], vaOff[2], bpOff[2];
#pragma unroll
  for (int F = 0; F < 2; ++F) {
    int Lr = 8 * F + (qq >> 1);
    afOff[F] = Lr * 128 + ((((qq & 1) * 4 + g) ^ (Lr & 7)) << 4);
  }
#pragma unroll
  for (int hd = 0; hd < 2; ++hd) {
    int d = hd * 16 + qq;
    vaOff[hd] = d * 64 + (((g ^ ((d ^ (d >> 2)) & 3))) << 4);
  }
#pragma unroll
  for (int F = 0; F < 2; ++F) {
    int row = wq * 16 + qq;
    bpOff[F] = row * 128 + (((2 * g + F) ^ (row & 7)) << 4);
  }
  const char* sBMr = sBM + (wq >> 2) * 4096;   // this wave-group's bm copy

#define STAGE(tt, dbi) do { \
    dma16(roleSrc + (size_t)(tt) * roleStride, roleDst + (dbi) * 4096); \
    dma16(pSrc0 + (size_t)(tt) * 128, sP + (dbi) * 16384 + wq * 2048); \
    dma16(pSrc1 + (size_t)(tt) * 128, sP + (dbi) * 16384 + wq * 2048 + 1024); \
  } while (0)

  f32x4 o00 = {}, o01 = {}, o10 = {}, o11 = {};
  float l0 = 0.f, l1 = 0.f;

  // prologue: stage bias_mask khq-quarter, 2 copies (waves 0-3 / 4-7), + tile 0
  {
    int p = wq & 3;
    dma16((const char*)bias_mask + (p >> 1) * 8192 + khq * 2048 + (p & 1) * 1024 + l * 16,
          sBM + (wq >> 2) * 4096 + p * 1024);
  }
  STAGE(0, 0);

#pragma unroll 1
  for (int t = 0; t < 16; ++t) {
    const int bi = t & 1;
    if (t < 15) {
      STAGE(t + 1, bi ^ 1);
      asm volatile("s_waitcnt vmcnt(3)" ::: "memory");
    } else {
      asm volatile("s_waitcnt vmcnt(0)" ::: "memory");
    }
    __builtin_amdgcn_s_barrier();
    __builtin_amdgcn_sched_barrier(0);

    const char* bP = sP + bi * 16384;
    f32x4 bp0 = *(const f32x4*)(bP + bpOff[0]);
    f32x4 bp1 = *(const f32x4*)(bP + bpOff[1]);
    const int bmOff = t * 128 + 32 * g;          // bytes: (t*32 + 8g)*4

    // ================= b = 0 =================
    {
      const char* bK = sK + bi * 4096;
      const char* bV = sV + bi * 4096;
      bf16x8 af0 = *(const bf16x8*)(bK + afOff[0]);
      bf16x8 af1 = *(const bf16x8*)(bK + afOff[1]);
      f32x4 z = {};
      f32x4 s0 = mfma32(af0, qf0, z);
      f32x4 s1 = mfma32(af1, qf0, z);
      f32x4 bm0 = *(const f32x4*)(sBMr + bmOff);
      f32x4 bm1 = *(const f32x4*)(sBMr + bmOff + 16);
#pragma unroll
      for (int r = 0; r < 4; ++r) {
        s0[r] += bp0[r] + bm0[r];
        s1[r] += bp1[r] + bm1[r];
      }
      U8 bu;
      {
        float p0 = __expf(s0[0]), p1 = __expf(s0[1]);
        float p2 = __expf(s0[2]), p3 = __expf(s0[3]);
        l0 += (p0 + p1) + (p2 + p3);
        bu.u[0] = cvt2bf(p0, p1); bu.u[1] = cvt2bf(p2, p3);
        p0 = __expf(s1[0]); p1 = __expf(s1[1]);
        p2 = __expf(s1[2]); p3 = __expf(s1[3]);
        l0 += (p0 + p1) + (p2 + p3);
        bu.u[2] = cvt2bf(p0, p1); bu.u[3] = cvt2bf(p2, p3);
      }
      bf16x8 va0 = *(const bf16x8*)(bV + vaOff[0]);
      bf16x8 va1 = *(const bf16x8*)(bV + vaOff[1]);
      o00 = mfma32(va0, bu.v, o00);
      o01 = mfma32(va1, bu.v, o01);
    }
    // ================= b = 1 =================
    {
      const char* bK = sK + bi * 4096 + 2048;
      const char* bV = sV + bi * 4096 + 2048;
      bf16x8 af0 = *(const bf16x8*)(bK + afOff[0]);
      bf16x8 af1 = *(const bf16x8*)(bK + afOff[1]);
      f32x4 z = {};
      f32x4 s0 = mfma32(af0, qf1, z);
      f32x4 s1 = mfma32(af1, qf1, z);
      f32x4 bm0 = *(const f32x4*)(sBMr + 2048 + bmOff);
      f32x4 bm1 = *(const f32x4*)(sBMr + 2048 + bmOff + 16);
#pragma unroll
      for (int r = 0; r < 4; ++r) {
        s0[r] += bp0[r] + bm0[r];
        s1[r] += bp1[r] + bm1[r];
      }
      U8 bu;
      {
        float p0 = __expf(s0[0]), p1 = __expf(s0[1]);
        float p2 = __expf(s0[2]), p3 = __expf(s0[3]);
        l1 += (p0 + p1) + (p2 + p3);
        bu.u[0] = cvt2bf(p0, p1); bu.u[1] = cvt2bf(p2, p3);
        p0 = __expf(s1[0]); p1 = __expf(s1[1]);
        p2 = __expf(s1[2]); p3 = __expf(s1[3]);
        l1 += (p0 + p1) + (p2 + p3);
        bu.u[2] = cvt2bf(p0, p1); bu.u[3] = cvt2bf(p2, p3);
      }
      bf16x8 va0 = *(const bf16x8*)(bV + vaOff[0]);
      bf16x8 va1 = *(const bf16x8*)(bV + vaOff[1]);
      o10 = mfma32(va0, bu.v, o10);
      o11 = mfma32(va1, bu.v, o11);
    }

    __builtin_amdgcn_sched_barrier(0);
    __builtin_amdgcn_s_barrier();
  }
#undef STAGE

  // ---- epilogue: per b: reduce l, transpose O^T via LDS, write partials ----
  l0 += __shfl_xor(l0, 16, 64);
  l0 += __shfl_xor(l0, 32, 64);
  l1 += __shfl_xor(l1, 16, 64);
  l1 += __shfl_xor(l1, 32, 64);
#pragma unroll
  for (int b = 0; b < 2; ++b) {
    f32x4 oa = b ? o10 : o00;
    f32x4 ob = b ? o11 : o01;
    float lr = b ? l1 : l0;
    __syncthreads();
    float* se = (float*)LDS + wq * 576;      // [16 q][36 d] per wave (8x2304B)
#pragma unroll
    for (int r = 0; r < 4; ++r) {
      se[qq * 36 + 4 * g + r]      = oa[r];   // d = 4g+r
      se[qq * 36 + 16 + 4 * g + r] = ob[r];   // d = 16+4g+r
    }
    if (g == 0) l_ws[khq * 32768 + b * 16384 + h * 2048 + q_glob] = lr;
    __syncthreads();
    const int qrow = l >> 2, pc = l & 3;
    const float* sr = (float*)LDS + wq * 576 + qrow * 36 + pc * 8;
    f32x4 x0 = *(const f32x4*)sr;
    f32x4 x1 = *(const f32x4*)(sr + 4);
    const int q_out = qt * 128 + wq * 16 + qrow;
    float* dst = O_ws + ((size_t)((khq * 2 + b) * HQ + q_out)) * NC + h * ND + pc * 8;
    *(f32x4*)dst = x0;
    *(f32x4*)(dst + 4) = x1;
  }
}

// ---------------- output projection (+ 4-way partial merge + gate) --------
// grid 256: bx&63 = Mblock, bx>>6 = Nblock. Head for column group ks is ks.
__global__ __launch_bounds__(256) void outproj_kernel(
    const float* __restrict__ O_ws, const float* __restrict__ l_ws,
    const float* __restrict__ g_ws, const float* __restrict__ Wo,
    const float* __restrict__ bo, float* __restrict__ out)
{
  const int bx = blockIdx.x;
  const int Mb = bx & 63, Nb = bx >> 6;
  const int Mbase = Mb * 64, Nbase = Nb * 64;
  __shared__ __align__(16) uint16_t smem2[4096];
  uint16_t* sA = smem2;
  uint16_t* sB = smem2 + 2048;
  const int tid = threadIdx.x;
  const int l = tid & 63, w = tid >> 6;
  const int qq = l & 15, g = l >> 4;
  const int row = tid >> 2, gp = tid & 3;
  const int m = Mbase + row, bb2 = m >> 11, qloc = m & 2047;
  f32x4 acc[4] = {};
  for (int ks = 0; ks < 8; ++ks) {
    const size_t lbase = (size_t)bb2 * 16384 + (size_t)ks * 2048 + qloc;
    const float inv = 1.f / (l_ws[lbase] + l_ws[32768 + lbase] +
                             l_ws[65536 + lbase] + l_ws[98304 + lbase]);
    const int col = ks * 32 + gp * 8;
    f32x4 a0 = {}, a1 = {};
#pragma unroll
    for (int kq = 0; kq < 4; ++kq) {
      const float* op = O_ws + ((size_t)((kq * 2 + bb2) * HQ + qloc)) * NC + col;
      f32x4 t0 = *(const f32x4*)op;
      f32x4 t1 = *(const f32x4*)(op + 4);
#pragma unroll
      for (int r = 0; r < 4; ++r) { a0[r] += t0[r]; a1[r] += t1[r]; }
    }
    const float* gpp = g_ws + ((size_t)(bb2 * HQ + qloc)) * NC + col;
    f32x4 g0 = *(const f32x4*)gpp;      f32x4 g1 = *(const f32x4*)(gpp + 4);
#pragma unroll
    for (int r = 0; r < 4; ++r) {
      a0[r] = a0[r] * inv * g0[r];
      a1[r] = a1[r] * inv * g1[r];
    }
    const float* wsrc = Wo + (size_t)(Nbase + row) * 256 + ks * 32 + gp * 8;
    f32x4 w0 = *(const f32x4*)wsrc;
    f32x4 w1 = *(const f32x4*)(wsrc + 4);
    U8 ua, uw;
    ua.u[0] = pack2bf(a0[0], a0[1]); ua.u[1] = pack2bf(a0[2], a0[3]);
    ua.u[2] = pack2bf(a1[0], a1[1]); ua.u[3] = pack2bf(a1[2], a1[3]);
    uw.u[0] = pack2bf(w0[0], w0[1]); uw.u[1] = pack2bf(w0[2], w0[3]);
    uw.u[2] = pack2bf(w1[0], w1[1]); uw.u[3] = pack2bf(w1[2], w1[3]);
    __syncthreads();
    *(bf16x8*)((char*)sA + swz64(row, gp)) = ua.v;
    *(bf16x8*)((char*)sB + swz64(row, gp)) = uw.v;
    __syncthreads();
    bf16x8 a = *(bf16x8*)((char*)sA + swz64(w * 16 + qq, g));
#pragma unroll
    for (int nf = 0; nf < 4; ++nf) {
      bf16x8 bb = *(bf16x8*)((char*)sB + swz64(nf * 16 + qq, g));
      acc[nf] = mfma32(a, bb, acc[nf]);
    }
  }
#pragma unroll
  for (int nf = 0; nf < 4; ++nf) {
    int n = Nbase + nf * 16 + qq;
    float bias = bo[n];
#pragma unroll
    for (int r = 0; r < 4; ++r) {
      int mm = Mbase + w * 16 + 4 * g + r;
      out[(size_t)mm * NC + n] = acc[nf][r] + bias;
    }
  }
}

extern "C" void kernel_launch(void* const* d_in, const int* in_sizes, int n_in,
                              void* d_out, int out_size, void* d_ws, size_t ws_size,
                              hipStream_t stream) {
  (void)in_sizes; (void)n_in; (void)out_size; (void)ws_size;
  const float* qx        = (const float*)d_in[0];
  const float* kvx       = (const float*)d_in[1];
  const float* bias_mask = (const float*)d_in[2];
  const float* bias_pair = (const float*)d_in[3];
  const float* Wq        = (const float*)d_in[4];
  const float* Wk        = (const float*)d_in[5];
  const float* Wv        = (const float*)d_in[6];
  const float* Wo        = (const float*)d_in[7];
  const float* bo        = (const float*)d_in[8];
  const float* Wg        = (const float*)d_in[9];
  const float* bg        = (const float*)d_in[10];

  char* ws = (char*)d_ws;
  uint16_t* q_p  = (uint16_t*)(ws);                       // 2 MB
  uint16_t* k_p  = (uint16_t*)(ws + (2u << 20));          // 2 MB
  uint16_t* v_p  = (uint16_t*)(ws + (4u << 20));          // 2 MB  [B,H,D,K]
  float*    g_ws = (float*)   (ws + (6u << 20));          // 4 MB
  float*    O_ws = (float*)   (ws + (10u << 20));         // 16 MB [khq,b,Q,HD] f32
  float*    l_ws = (float*)   (ws + (26u << 20));         // 512 KB [khq,b,h,Q]
  float* out = (float*)d_out;

  proj_kernel<<<dim3(1024), dim3(256), 0, stream>>>(qx, kvx, Wq, Wk, Wv, Wg, bg,
                                                    q_p, k_p, v_p, g_ws);
  attn_kernel<<<dim3(512), dim3(512), 0, stream>>>(q_p, k_p, v_p, bias_mask,
                                                   bias_pair, O_ws, l_ws);
  outproj_kernel<<<dim3(256), dim3(256), 0, stream>>>(O_ws, l_ws, g_ws, Wo, bo, out);
}

// Round 20
// 53.511 us; speedup vs baseline: 1.7946x; 1.0111x over previous
//
#include <hip/hip_runtime.h>
#include <hip/hip_bf16.h>
#include <stdint.h>
#include <math.h>

typedef __attribute__((ext_vector_type(8))) short bf16x8;
typedef __attribute__((ext_vector_type(4))) float f32x4;

#define HQ 2048
#define HK 2048
#define NH 8
#define ND 32
#define NC 256

union U8 { uint32_t u[4]; bf16x8 v; };

__device__ __forceinline__ uint16_t f2bf(float f) {
  uint32_t u = __float_as_uint(f);
  u += 0x7FFFu + ((u >> 16) & 1u);   // RNE
  return (uint16_t)(u >> 16);
}
__device__ __forceinline__ uint32_t pack2bf(float a, float b) {
  return (uint32_t)f2bf(a) | ((uint32_t)f2bf(b) << 16);
}
// single-instruction RNE pack (v_cvt_pk_bf16_f32): lo=bf16(a), hi=bf16(b)
__device__ __forceinline__ uint32_t cvt2bf(float a, float b) {
  uint32_t r;
  asm("v_cvt_pk_bf16_f32 %0, %1, %2" : "=v"(r) : "v"(a), "v"(b));
  return r;
}
// 64B rows (32 bf16), 4 pieces of 16B
__device__ __forceinline__ int swz64(int row, int piece) {
  int s = (((row >> 3) & 1) << 1) | ((row >> 1) & 1);
  return row * 64 + ((piece ^ s) << 4);
}
__device__ __forceinline__ f32x4 mfma32(bf16x8 a, bf16x8 b, f32x4 c) {
  return __builtin_amdgcn_mfma_f32_16x16x32_bf16(a, b, c, 0, 0, 0);
}
// async global->LDS DMA, 16B per lane; dst wave-uniform (HW: dst+lane*16)
__device__ __forceinline__ void dma16(const void* g, void* l) {
  __builtin_amdgcn_global_load_lds(
      (const __attribute__((address_space(1))) uint32_t*)g,
      (__attribute__((address_space(3))) uint32_t*)l, 16, 0, 0);
}

// ---------------- projections: q,k,v,g -----------------------------------
// grid 1024: bx&63 = Mblock(64), (bx>>6)&3 = Nblock(4), bx>>8 = proj id
// (4 blocks/CU; X re-reads across Nb are L2 hits - not HBM traffic.)
__global__ __launch_bounds__(256) void proj_kernel(
    const float* __restrict__ qx, const float* __restrict__ kvx,
    const float* __restrict__ Wq, const float* __restrict__ Wk,
    const float* __restrict__ Wv, const float* __restrict__ Wg,
    const float* __restrict__ bg,
    uint16_t* __restrict__ q_p, uint16_t* __restrict__ k_p,
    uint16_t* __restrict__ v_p, float* __restrict__ g_ws)
{
  const int bx = blockIdx.x;
  const int Mb = bx & 63, Nb = (bx >> 6) & 3, p = bx >> 8;
  const int Mbase = Mb * 64, Nbase = Nb * 64;
  const float* X = (p == 0 || p == 3) ? qx : kvx;
  const float* W = (p == 0) ? Wq : (p == 1) ? Wk : (p == 2) ? Wv : Wg;

  __shared__ __align__(16) uint16_t smem[4096]; // 8KB: X tile | W tile
  uint16_t* sX = smem;
  uint16_t* sW = smem + 2048;

  const int tid = threadIdx.x;
  const int l = tid & 63, w = tid >> 6;
  const int qq = l & 15, g = l >> 4;
  const int row = tid >> 2, gp = tid & 3;

  f32x4 acc[4] = {};

  for (int ks = 0; ks < 8; ++ks) {
    const float* xs = X + (size_t)(Mbase + row) * 256 + ks * 32 + gp * 8;
    f32x4 x0 = *(const f32x4*)xs;
    f32x4 x1 = *(const f32x4*)(xs + 4);
    const float* ws_ = W + (size_t)(Nbase + row) * 256 + ks * 32 + gp * 8;
    f32x4 w0 = *(const f32x4*)ws_;
    f32x4 w1 = *(const f32x4*)(ws_ + 4);
    U8 ux, uw;
    ux.u[0] = pack2bf(x0[0], x0[1]); ux.u[1] = pack2bf(x0[2], x0[3]);
    ux.u[2] = pack2bf(x1[0], x1[1]); ux.u[3] = pack2bf(x1[2], x1[3]);
    uw.u[0] = pack2bf(w0[0], w0[1]); uw.u[1] = pack2bf(w0[2], w0[3]);
    uw.u[2] = pack2bf(w1[0], w1[1]); uw.u[3] = pack2bf(w1[2], w1[3]);
    __syncthreads();
    *(bf16x8*)((char*)sX + swz64(row, gp)) = ux.v;
    *(bf16x8*)((char*)sW + swz64(row, gp)) = uw.v;
    __syncthreads();
    bf16x8 a = *(bf16x8*)((char*)sX + swz64(w * 16 + qq, g));
#pragma unroll
    for (int nf = 0; nf < 4; ++nf) {
      bf16x8 bb = *(bf16x8*)((char*)sW + swz64(nf * 16 + qq, g));
      acc[nf] = mfma32(a, bb, acc[nf]);
    }
  }

  if (p == 2) {
    // transpose epilogue -> v_p[B,H,D,K]
    __syncthreads();
#pragma unroll
    for (int nf = 0; nf < 4; ++nf) {
      int n_loc = nf * 16 + qq;
#pragma unroll
      for (int r = 0; r < 4; ++r) {
        int m_loc = w * 16 + 4 * g + r;
        int byte = n_loc * 128 + ((((m_loc >> 3) ^ (n_loc & 7)) << 4)) + (m_loc & 7) * 2;
        *(uint16_t*)((char*)smem + byte) = f2bf(acc[nf][r]);
      }
    }
    __syncthreads();
    const int n_loc = tid >> 2, mp = tid & 3;
    const int ng = Nbase + n_loc;
    const int hh = ng >> 5, dd = ng & 31;
    const int bb_ = Mbase >> 11;
#pragma unroll
    for (int jj = 0; jj < 2; ++jj) {
      int piece = mp * 2 + jj;
      bf16x8 vv = *(bf16x8*)((char*)smem + n_loc * 128 + ((piece ^ (n_loc & 7)) << 4));
      int seq = (Mbase & 2047) + piece * 8;
      *(bf16x8*)(v_p + ((size_t)(bb_ * NH + hh) * ND + dd) * (size_t)HK + seq) = vv;
    }
    return;
  }

#pragma unroll
  for (int nf = 0; nf < 4; ++nf) {
    int n = Nbase + nf * 16 + qq;
#pragma unroll
    for (int r = 0; r < 4; ++r) {
      int m = Mbase + w * 16 + 4 * g + r;
      float val = acc[nf][r];
      if (p == 0) {
        val *= 0.17677669529663687f; // 1/sqrt(32)
        int bb_ = m >> 11, seq = m & 2047, hh = n >> 5, dd = n & 31;
        q_p[((size_t)(bb_ * NH + hh) * HQ + seq) * ND + dd] = f2bf(val);
      } else if (p == 1) {
        int bb_ = m >> 11, seq = m & 2047, hh = n >> 5, dd = n & 31;
        k_p[((size_t)(bb_ * NH + hh) * HK + seq) * ND + dd] = f2bf(val);
      } else { // p == 3 : gate
        g_ws[(size_t)m * NC + n] = 1.f / (1.f + __expf(-(val + bg[n])));
      }
    }
  }
}

// ---------------- fused attention -----------------------------------------
// grid 512 x 512 thr: bx&3=khq (K quarter, 512 k), (bx>>2)&7=h, bx>>5=qt
// (128 q rows). 8 waves; wave wq owns q-rows qt*128+wq*16..+15, BOTH batches.
// k-tile 32 -> 16 iters. Per iter per wave exactly 3 DMAs -> counted vmcnt(3).
// LDS 56KB -> 2 blocks/CU. v_cvt_pk_bf16_f32 packing. s_setprio(1) around the
// compute cluster (T5: waves have role diversity - K-stagers vs V-stagers +
// 2 free-running blocks/CU - so priority arbitration has something to do).
// Unnormalized softmax; 4-way K-split partials merged in outproj.
__global__ __launch_bounds__(512, 4) void attn_kernel(
    const uint16_t* __restrict__ q_p, const uint16_t* __restrict__ k_p,
    const uint16_t* __restrict__ v_p, const float* __restrict__ bias_mask,
    const float* __restrict__ bias_pair,
    float* __restrict__ O_ws, float* __restrict__ l_ws)
{
  const int bx = blockIdx.x;
  const int khq = bx & 3, h = (bx >> 2) & 7, qt = bx >> 5;

  __shared__ __align__(16) char LDS[57344];    // 56 KB
  char* sK = LDS;             // 2buf x 2b x 2KB = 8KB
  char* sV = LDS + 8192;      // 2buf x 2b x 2KB = 8KB
  char* sP = LDS + 16384;     // 2buf x 16KB     = 32KB
  char* sBM = LDS + 49152;    // 2 copies x (2b x 2KB) = 8KB

  const int tid = threadIdx.x;
  const int l = tid & 63, wq = tid >> 6;       // wq 0..7
  const int qq = l & 15, g = l >> 4;
  const int q_glob = qt * 128 + wq * 16 + qq;

  // Q B-fragments for both batches (hoisted)
  bf16x8 qf0 = *(const bf16x8*)(q_p + ((size_t)h * HQ + q_glob) * ND + g * 8);
  bf16x8 qf1 = *(const bf16x8*)(q_p + ((size_t)(NH + h) * HQ + q_glob) * ND + g * 8);

  // ---- role staging: waves 0-3 stage K, waves 4-7 stage V ----
  const int rw = wq & 3;                 // role sub-index
  const int bsel = rw >> 1, hsel = rw & 1;
  const char* roleSrc;
  int roleStride;
  char* roleDst;                          // + dbi*4096 at use
  if (wq < 4) {
    int B = hsel * 1024 + l * 16;
    int Lr = B >> 7, cpos = l & 7;
    int hp = cpos ^ (Lr & 7);
    int half = hp >> 2, pc = hp & 3;
    int s = Lr * 2 + half, F = s >> 4, qs = s & 15;
    int krow = 8 * (qs >> 2) + (qs & 3) + 4 * F;
    roleSrc = (const char*)k_p + (size_t)(bsel * NH + h) * HK * ND * 2
              + khq * 32768 + krow * 64 + pc * 16;
    roleStride = 2048;
    roleDst = sK + bsel * 2048 + hsel * 1024;
  } else {
    int B = hsel * 1024 + l * 16;
    int d = B >> 6, cpos = l & 3;
    int gs = cpos ^ ((d ^ (d >> 2)) & 3);
    roleSrc = (const char*)v_p + (size_t)(bsel * NH + h) * ND * (size_t)HK * 2
              + khq * 1024 + (size_t)d * (HK * 2) + gs * 16;
    roleStride = 64;
    roleDst = sV + bsel * 2048 + hsel * 1024;
  }
  // bias_pair: each wave stages its own 16 q-rows x 128B = 2 x 1KB dma.
  const char* pSrc0; const char* pSrc1;
  {
    const char* bpBlk = (const char*)bias_pair
        + ((size_t)h * HQ + qt * 128) * (size_t)HK * 4 + khq * 2048;
#define BP_SRC(jj) ({ int row = wq * 16 + (jj) * 8 + (l >> 3); \
                      int gs = (l & 7) ^ (row & 7); \
                      bpBlk + (size_t)row * (HK * 4) + gs * 16; })
    pSrc0 = BP_SRC(0); pSrc1 = BP_SRC(1);
#undef BP_SRC
  }

  // ---- reader byte offsets (loop-invariant) ----
  int afOff[2], vaOff[2], bpOff[2];
#pragma unroll
  for (int F = 0; F < 2; ++F) {
    int Lr = 8 * F + (qq >> 1);
    afOff[F] = Lr * 128 + ((((qq & 1) * 4 + g) ^ (Lr & 7)) << 4);
  }
#pragma unroll
  for (int hd = 0; hd < 2; ++hd) {
    int d = hd * 16 + qq;
    vaOff[hd] = d * 64 + (((g ^ ((d ^ (d >> 2)) & 3))) << 4);
  }
#pragma unroll
  for (int F = 0; F < 2; ++F) {
    int row = wq * 16 + qq;
    bpOff[F] = row * 128 + (((2 * g + F) ^ (row & 7)) << 4);
  }
  const char* sBMr = sBM + (wq >> 2) * 4096;   // this wave-group's bm copy

#define STAGE(tt, dbi) do { \
    dma16(roleSrc + (size_t)(tt) * roleStride, roleDst + (dbi) * 4096); \
    dma16(pSrc0 + (size_t)(tt) * 128, sP + (dbi) * 16384 + wq * 2048); \
    dma16(pSrc1 + (size_t)(tt) * 128, sP + (dbi) * 16384 + wq * 2048 + 1024); \
  } while (0)

  f32x4 o00 = {}, o01 = {}, o10 = {}, o11 = {};
  float l0 = 0.f, l1 = 0.f;

  // prologue: stage bias_mask khq-quarter, 2 copies (waves 0-3 / 4-7), + tile 0
  {
    int p = wq & 3;
    dma16((const char*)bias_mask + (p >> 1) * 8192 + khq * 2048 + (p & 1) * 1024 + l * 16,
          sBM + (wq >> 2) * 4096 + p * 1024);
  }
  STAGE(0, 0);

#pragma unroll 1
  for (int t = 0; t < 16; ++t) {
    const int bi = t & 1;
    if (t < 15) {
      STAGE(t + 1, bi ^ 1);
      asm volatile("s_waitcnt vmcnt(3)" ::: "memory");
    } else {
      asm volatile("s_waitcnt vmcnt(0)" ::: "memory");
    }
    __builtin_amdgcn_s_barrier();
    __builtin_amdgcn_sched_barrier(0);
    __builtin_amdgcn_s_setprio(1);

    const char* bP = sP + bi * 16384;
    f32x4 bp0 = *(const f32x4*)(bP + bpOff[0]);
    f32x4 bp1 = *(const f32x4*)(bP + bpOff[1]);
    const int bmOff = t * 128 + 32 * g;          // bytes: (t*32 + 8g)*4

    // ================= b = 0 =================
    {
      const char* bK = sK + bi * 4096;
      const char* bV = sV + bi * 4096;
      bf16x8 af0 = *(const bf16x8*)(bK + afOff[0]);
      bf16x8 af1 = *(const bf16x8*)(bK + afOff[1]);
      f32x4 z = {};
      f32x4 s0 = mfma32(af0, qf0, z);
      f32x4 s1 = mfma32(af1, qf0, z);
      f32x4 bm0 = *(const f32x4*)(sBMr + bmOff);
      f32x4 bm1 = *(const f32x4*)(sBMr + bmOff + 16);
#pragma unroll
      for (int r = 0; r < 4; ++r) {
        s0[r] += bp0[r] + bm0[r];
        s1[r] += bp1[r] + bm1[r];
      }
      U8 bu;
      {
        float p0 = __expf(s0[0]), p1 = __expf(s0[1]);
        float p2 = __expf(s0[2]), p3 = __expf(s0[3]);
        l0 += (p0 + p1) + (p2 + p3);
        bu.u[0] = cvt2bf(p0, p1); bu.u[1] = cvt2bf(p2, p3);
        p0 = __expf(s1[0]); p1 = __expf(s1[1]);
        p2 = __expf(s1[2]); p3 = __expf(s1[3]);
        l0 += (p0 + p1) + (p2 + p3);
        bu.u[2] = cvt2bf(p0, p1); bu.u[3] = cvt2bf(p2, p3);
      }
      bf16x8 va0 = *(const bf16x8*)(bV + vaOff[0]);
      bf16x8 va1 = *(const bf16x8*)(bV + vaOff[1]);
      o00 = mfma32(va0, bu.v, o00);
      o01 = mfma32(va1, bu.v, o01);
    }
    // ================= b = 1 =================
    {
      const char* bK = sK + bi * 4096 + 2048;
      const char* bV = sV + bi * 4096 + 2048;
      bf16x8 af0 = *(const bf16x8*)(bK + afOff[0]);
      bf16x8 af1 = *(const bf16x8*)(bK + afOff[1]);
      f32x4 z = {};
      f32x4 s0 = mfma32(af0, qf1, z);
      f32x4 s1 = mfma32(af1, qf1, z);
      f32x4 bm0 = *(const f32x4*)(sBMr + 2048 + bmOff);
      f32x4 bm1 = *(const f32x4*)(sBMr + 2048 + bmOff + 16);
#pragma unroll
      for (int r = 0; r < 4; ++r) {
        s0[r] += bp0[r] + bm0[r];
        s1[r] += bp1[r] + bm1[r];
      }
      U8 bu;
      {
        float p0 = __expf(s0[0]), p1 = __expf(s0[1]);
        float p2 = __expf(s0[2]), p3 = __expf(s0[3]);
        l1 += (p0 + p1) + (p2 + p3);
        bu.u[0] = cvt2bf(p0, p1); bu.u[1] = cvt2bf(p2, p3);
        p0 = __expf(s1[0]); p1 = __expf(s1[1]);
        p2 = __expf(s1[2]); p3 = __expf(s1[3]);
        l1 += (p0 + p1) + (p2 + p3);
        bu.u[2] = cvt2bf(p0, p1); bu.u[3] = cvt2bf(p2, p3);
      }
      bf16x8 va0 = *(const bf16x8*)(bV + vaOff[0]);
      bf16x8 va1 = *(const bf16x8*)(bV + vaOff[1]);
      o10 = mfma32(va0, bu.v, o10);
      o11 = mfma32(va1, bu.v, o11);
    }

    __builtin_amdgcn_s_setprio(0);
    __builtin_amdgcn_sched_barrier(0);
    __builtin_amdgcn_s_barrier();
  }
#undef STAGE

  // ---- epilogue: per b: reduce l, transpose O^T via LDS, write partials ----
  l0 += __shfl_xor(l0, 16, 64);
  l0 += __shfl_xor(l0, 32, 64);
  l1 += __shfl_xor(l1, 16, 64);
  l1 += __shfl_xor(l1, 32, 64);
#pragma unroll
  for (int b = 0; b < 2; ++b) {
    f32x4 oa = b ? o10 : o00;
    f32x4 ob = b ? o11 : o01;
    float lr = b ? l1 : l0;
    __syncthreads();
    float* se = (float*)LDS + wq * 576;      // [16 q][36 d] per wave (8x2304B)
#pragma unroll
    for (int r = 0; r < 4; ++r) {
      se[qq * 36 + 4 * g + r]      = oa[r];   // d = 4g+r
      se[qq * 36 + 16 + 4 * g + r] = ob[r];   // d = 16+4g+r
    }
    if (g == 0) l_ws[khq * 32768 + b * 16384 + h * 2048 + q_glob] = lr;
    __syncthreads();
    const int qrow = l >> 2, pc = l & 3;
    const float* sr = (float*)LDS + wq * 576 + qrow * 36 + pc * 8;
    f32x4 x0 = *(const f32x4*)sr;
    f32x4 x1 = *(const f32x4*)(sr + 4);
    const int q_out = qt * 128 + wq * 16 + qrow;
    float* dst = O_ws + ((size_t)((khq * 2 + b) * HQ + q_out)) * NC + h * ND + pc * 8;
    *(f32x4*)dst = x0;
    *(f32x4*)(dst + 4) = x1;
  }
}

// ---------------- output projection (+ 4-way partial merge + gate) --------
// grid 256: bx&63 = Mblock, bx>>6 = Nblock. Head for column group ks is ks.
__global__ __launch_bounds__(256) void outproj_kernel(
    const float* __restrict__ O_ws, const float* __restrict__ l_ws,
    const float* __restrict__ g_ws, const float* __restrict__ Wo,
    const float* __restrict__ bo, float* __restrict__ out)
{
  const int bx = blockIdx.x;
  const int Mb = bx & 63, Nb = bx >> 6;
  const int Mbase = Mb * 64, Nbase = Nb * 64;
  __shared__ __align__(16) uint16_t smem2[4096];
  uint16_t* sA = smem2;
  uint16_t* sB = smem2 + 2048;
  const int tid = threadIdx.x;
  const int l = tid & 63, w = tid >> 6;
  const int qq = l & 15, g = l >> 4;
  const int row = tid >> 2, gp = tid & 3;
  const int m = Mbase + row, bb2 = m >> 11, qloc = m & 2047;
  f32x4 acc[4] = {};
  for (int ks = 0; ks < 8; ++ks) {
    const size_t lbase = (size_t)bb2 * 16384 + (size_t)ks * 2048 + qloc;
    const float inv = 1.f / (l_ws[lbase] + l_ws[32768 + lbase] +
                             l_ws[65536 + lbase] + l_ws[98304 + lbase]);
    const int col = ks * 32 + gp * 8;
    f32x4 a0 = {}, a1 = {};
#pragma unroll
    for (int kq = 0; kq < 4; ++kq) {
      const float* op = O_ws + ((size_t)((kq * 2 + bb2) * HQ + qloc)) * NC + col;
      f32x4 t0 = *(const f32x4*)op;
      f32x4 t1 = *(const f32x4*)(op + 4);
#pragma unroll
      for (int r = 0; r < 4; ++r) { a0[r] += t0[r]; a1[r] += t1[r]; }
    }
    const float* gpp = g_ws + ((size_t)(bb2 * HQ + qloc)) * NC + col;
    f32x4 g0 = *(const f32x4*)gpp;      f32x4 g1 = *(const f32x4*)(gpp + 4);
#pragma unroll
    for (int r = 0; r < 4; ++r) {
      a0[r] = a0[r] * inv * g0[r];
      a1[r] = a1[r] * inv * g1[r];
    }
    const float* wsrc = Wo + (size_t)(Nbase + row) * 256 + ks * 32 + gp * 8;
    f32x4 w0 = *(const f32x4*)wsrc;
    f32x4 w1 = *(const f32x4*)(wsrc + 4);
    U8 ua, uw;
    ua.u[0] = pack2bf(a0[0], a0[1]); ua.u[1] = pack2bf(a0[2], a0[3]);
    ua.u[2] = pack2bf(a1[0], a1[1]); ua.u[3] = pack2bf(a1[2], a1[3]);
    uw.u[0] = pack2bf(w0[0], w0[1]); uw.u[1] = pack2bf(w0[2], w0[3]);
    uw.u[2] = pack2bf(w1[0], w1[1]); uw.u[3] = pack2bf(w1[2], w1[3]);
    __syncthreads();
    *(bf16x8*)((char*)sA + swz64(row, gp)) = ua.v;
    *(bf16x8*)((char*)sB + swz64(row, gp)) = uw.v;
    __syncthreads();
    bf16x8 a = *(bf16x8*)((char*)sA + swz64(w * 16 + qq, g));
#pragma unroll
    for (int nf = 0; nf < 4; ++nf) {
      bf16x8 bb = *(bf16x8*)((char*)sB + swz64(nf * 16 + qq, g));
      acc[nf] = mfma32(a, bb, acc[nf]);
    }
  }
#pragma unroll
  for (int nf = 0; nf < 4; ++nf) {
    int n = Nbase + nf * 16 + qq;
    float bias = bo[n];
#pragma unroll
    for (int r = 0; r < 4; ++r) {
      int mm = Mbase + w * 16 + 4 * g + r;
      out[(size_t)mm * NC + n] = acc[nf][r] + bias;
    }
  }
}

extern "C" void kernel_launch(void* const* d_in, const int* in_sizes, int n_in,
                              void* d_out, int out_size, void* d_ws, size_t ws_size,
                              hipStream_t stream) {
  (void)in_sizes; (void)n_in; (void)out_size; (void)ws_size;
  const float* qx        = (const float*)d_in[0];
  const float* kvx       = (const float*)d_in[1];
  const float* bias_mask = (const float*)d_in[2];
  const float* bias_pair = (const float*)d_in[3];
  const float* Wq        = (const float*)d_in[4];
  const float* Wk        = (const float*)d_in[5];
  const float* Wv        = (const float*)d_in[6];
  const float* Wo        = (const float*)d_in[7];
  const float* bo        = (const float*)d_in[8];
  const float* Wg        = (const float*)d_in[9];
  const float* bg        = (const float*)d_in[10];

  char* ws = (char*)d_ws;
  uint16_t* q_p  = (uint16_t*)(ws);                       // 2 MB
  uint16_t* k_p  = (uint16_t*)(ws + (2u << 20));          // 2 MB
  uint16_t* v_p  = (uint16_t*)(ws + (4u << 20));          // 2 MB  [B,H,D,K]
  float*    g_ws = (float*)   (ws + (6u << 20));          // 4 MB
  float*    O_ws = (float*)   (ws + (10u << 20));         // 16 MB [khq,b,Q,HD] f32
  float*    l_ws = (float*)   (ws + (26u << 20));         // 512 KB [khq,b,h,Q]
  float* out = (float*)d_out;

  proj_kernel<<<dim3(1024), dim3(256), 0, stream>>>(qx, kvx, Wq, Wk, Wv, Wg, bg,
                                                    q_p, k_p, v_p, g_ws);
  attn_kernel<<<dim3(512), dim3(512), 0, stream>>>(q_p, k_p, v_p, bias_mask,
                                                   bias_pair, O_ws, l_ws);
  outproj_kernel<<<dim3(256), dim3(256), 0, stream>>>(O_ws, l_ws, g_ws, Wo, bo, out);
}